// Round 8
// baseline (581.505 us; speedup 1.0000x reference)
//
#include <hip/hip_runtime.h>
#include <hip/hip_bf16.h>
#include <hip/hip_cooperative_groups.h>
#include <stdint.h>

namespace cg = cooperative_groups;

// ---------------------------------------------------------------------------
// SNN: x[512,784] -> FC(784->1024)+LIF -> FC(1024->1024)+LIF -> FC(1024->10)+LIF
// T=32, tau=2, vth=1, hard reset. Out = spike counts [512,10].
//
// Verified structure (R5-R7, absmax=0): layer-0 LIF is exactly periodic
// (class n = ctz(word)+1), layer-1 current is a divisor sum over class
// weight-sums; cur0 via exact 3-way bf16 split (6 cross-terms) MFMA GEMM,
// split-K x10 for occupancy.
//
// R7 lesson: harness 0xAA-fill of the 256MB ws (42us, HBM-bound) is inside
// the timed window -> fixed floor. Controllable: ~50us kernels + ~25us of
// 6 inter-kernel gaps. Fix: fuse all stages into ONE cooperative kernel
// (512 blocks x 256 thr = 2 blocks/CU co-resident, grid.sync between
// stages). Fallback to the proven 7-kernel path if cooperative launch is
// rejected (e.g. under graph capture).
// ---------------------------------------------------------------------------

typedef __bf16 bf16x8 __attribute__((ext_vector_type(8)));
typedef float  f32x4  __attribute__((ext_vector_type(4)));

__device__ __forceinline__ void gload16(const void* g, void* l) {
  __builtin_amdgcn_global_load_lds((const __attribute__((address_space(1))) void*)g,
                                   (__attribute__((address_space(3))) void*)l,
                                   16, 0, 0);
}

__device__ __forceinline__ void bsplit3(float v, __hip_bfloat16& h,
                                        __hip_bfloat16& m, __hip_bfloat16& l) {
  h = __float2bfloat16(v);
  float r1 = v - __bfloat162float(h);
  m = __float2bfloat16(r1);
  float r2 = r1 - __bfloat162float(m);
  l = __float2bfloat16(r2);
}

// ======================= fused cooperative mega-kernel ======================
struct SM_c0 { int whist[16][33]; int clstot[33]; int clsofs[34]; int wofs[16][33]; };
struct SM_l1 { unsigned short sidx[1024]; int sseg[33]; int wtot[4]; int wbase[4]; };
struct SM_l2 { unsigned sidx[1024]; unsigned swrd[1024]; float scur[320]; };

__global__ __launch_bounds__(256, 2) void snn_mega_k(
    const float* __restrict__ x, const float* __restrict__ W0,
    const float* __restrict__ b0, const float* __restrict__ W1,
    const float* __restrict__ b1, const float* __restrict__ W2,
    const float* __restrict__ b2, float* __restrict__ out,
    __hip_bfloat16* __restrict__ Ax, __hip_bfloat16* __restrict__ Bw,
    float* __restrict__ Cpart, float* __restrict__ W1T,
    unsigned short* __restrict__ lidx16, int* __restrict__ segs,
    unsigned* __restrict__ l2idx, unsigned* __restrict__ l2wrd,
    int* __restrict__ n2t) {
  __shared__ __align__(16) char smem[16512];
  const int bid = blockIdx.x;    // 512
  const int tid = threadIdx.x;   // 256
  cg::grid_group grid = cg::this_grid();

  // ---- S1: bf16 splits of x,W0 + W1 transpose (grid-stride) ---------------
  for (int i = bid * 256 + tid; i < 512 * 800; i += 512 * 256) {
    int m = i / 800, k = i - m * 800;
    float v = (k < 784) ? x[(size_t)m * 784 + k] : 0.f;
    __hip_bfloat16 h, mm, l;
    bsplit3(v, h, mm, l);
    size_t base = (size_t)m * 4800;
    Ax[base + k] = h;        Ax[base + 800 + k] = h;
    Ax[base + 1600 + k] = mm; Ax[base + 2400 + k] = mm;
    Ax[base + 3200 + k] = h;  Ax[base + 4000 + k] = l;
  }
  for (int i = bid * 256 + tid; i < 1024 * 800; i += 512 * 256) {
    int n = i / 800, k = i - n * 800;
    float v = (k < 784) ? W0[(size_t)n * 784 + k] : 0.f;
    __hip_bfloat16 h, mm, l;
    bsplit3(v, h, mm, l);
    size_t base = (size_t)n * 4800;
    Bw[base + k] = h;         Bw[base + 800 + k] = mm;
    Bw[base + 1600 + k] = h;  Bw[base + 2400 + k] = mm;
    Bw[base + 3200 + k] = l;  Bw[base + 4000 + k] = h;
  }
  {
    float (*t)[33] = (float(*)[33])smem;
    int lx = tid & 31, ly = tid >> 5;     // 32 x 8
    for (int tt = bid; tt < 1024; tt += 512) {
      int c0 = (tt & 31) * 32, r0 = (tt >> 5) * 32;
#pragma unroll
      for (int i = 0; i < 32; i += 8)
        t[ly + i][lx] = W1[(size_t)(r0 + ly + i) * 1024 + (c0 + lx)];
      __syncthreads();
#pragma unroll
      for (int i = 0; i < 32; i += 8)
        W1T[(size_t)(c0 + ly + i) * 1024 + (r0 + lx)] = t[lx][ly + i];
      __syncthreads();
    }
  }
  __threadfence();
  grid.sync();

  // ---- S2: split-K MFMA GEMM cur0 partials (blocks 0..319) ----------------
  if (bid < 320) {
    __hip_bfloat16* As = (__hip_bfloat16*)smem;
    __hip_bfloat16* Bs = As + 128 * 32;
    const int bx = bid & 3, by = (bid >> 2) & 7, bz = bid >> 5;
    const int wave = tid >> 6, lane = tid & 63, quad = lane >> 4, l16 = lane & 15;
    const int wm = (wave >> 1) * 64, wn = (wave & 1) * 64;
    const int mbase = bx * 128, nbase = by * 128, kbase = bz * 480;
    const int srow = lane >> 2;
    const int gq = (lane & 3) ^ ((lane >> 3) & 3);
    const int swz = (l16 >> 1) & 3;
    f32x4 acc[4][4] = {};
    for (int kk = kbase; kk < kbase + 480; kk += 32) {
#pragma unroll
      for (int r = 0; r < 2; ++r) {
        int grp = wave * 2 + r;
        gload16(Ax + (size_t)(mbase + grp * 16 + srow) * 4800 + kk + gq * 8,
                (char*)As + grp * 1024);
        gload16(Bw + (size_t)(nbase + grp * 16 + srow) * 4800 + kk + gq * 8,
                (char*)Bs + grp * 1024);
      }
      __syncthreads();
      const __bf16* Ab = (const __bf16*)As;
      const __bf16* Bb = (const __bf16*)Bs;
      bf16x8 af[4], bfr[4];
#pragma unroll
      for (int i = 0; i < 4; ++i)
        af[i] = *(const bf16x8*)(Ab + (wm + i * 16 + l16) * 32 + ((quad ^ swz) * 8));
#pragma unroll
      for (int j = 0; j < 4; ++j)
        bfr[j] = *(const bf16x8*)(Bb + (wn + j * 16 + l16) * 32 + ((quad ^ swz) * 8));
#pragma unroll
      for (int i = 0; i < 4; ++i)
#pragma unroll
        for (int j = 0; j < 4; ++j)
          acc[i][j] = __builtin_amdgcn_mfma_f32_16x16x32_bf16(af[i], bfr[j], acc[i][j], 0, 0, 0);
      __syncthreads();
    }
    float* Cz = Cpart + (size_t)bz * 512 * 1024;
#pragma unroll
    for (int i = 0; i < 4; ++i)
#pragma unroll
      for (int j = 0; j < 4; ++j)
#pragma unroll
        for (int r = 0; r < 4; ++r) {
          int m = mbase + wm + i * 16 + quad * 4 + r;
          int n = nbase + wn + j * 16 + l16;
          Cz[(size_t)m * 1024 + n] = acc[i][j][r];
        }
  }
  __threadfence();
  grid.sync();

  // ---- S3: split-K reduce + LIF + class-grouped compaction (block=batch) --
  {
    SM_c0* c = (SM_c0*)smem;
    const int wave = tid >> 6, lane = tid & 63;
    int ncls[4];
    unsigned long long msk[4];
#pragma unroll 1
    for (int q = 0; q < 4; ++q) {
      int o = q * 256 + tid;
      float cur = 0.f;
#pragma unroll
      for (int z = 0; z < 10; ++z)
        cur += Cpart[(size_t)z * 524288 + (size_t)bid * 1024 + o];
      cur += b0[o];
      float v = 0.f;
      unsigned word = 0u;
#pragma unroll
      for (int t = 0; t < 32; ++t) {
        v = v + (cur - v) * 0.5f;        // exact: /2.0 == *0.5f
        if (v >= 1.0f) { word |= 1u << t; v = 0.f; }
      }
      ncls[q] = word ? (__builtin_ctz(word) + 1) : 0;
      msk[q] = 0ull;
#pragma unroll 1
      for (int cc = 1; cc <= 32; ++cc) {
        unsigned long long m = __ballot(ncls[q] == cc);
        if (lane == 0) c->whist[q * 4 + wave][cc] = __popcll(m);
        if (ncls[q] == cc) msk[q] = m;
      }
    }
    __syncthreads();
    if (tid < 32) {
      int cc = tid + 1, s = 0;
#pragma unroll
      for (int w = 0; w < 16; ++w) s += c->whist[w][cc];
      c->clstot[cc] = s;
    }
    __syncthreads();
    if (tid == 0) {
      int run = 0;
#pragma unroll
      for (int cc = 1; cc <= 32; ++cc) { c->clsofs[cc] = run; run += c->clstot[cc]; }
      c->clsofs[33] = run;
    }
    __syncthreads();
    if (tid < 32) {
      int cc = tid + 1, s = c->clsofs[cc];
#pragma unroll
      for (int w = 0; w < 16; ++w) { c->wofs[w][cc] = s; s += c->whist[w][cc]; }
    }
    __syncthreads();
#pragma unroll
    for (int q = 0; q < 4; ++q)
      if (ncls[q]) {
        int pos = c->wofs[q * 4 + wave][ncls[q]] +
                  __popcll(msk[q] & ((1ull << lane) - 1ull));
        lidx16[(size_t)bid * 1024 + pos] = (unsigned short)(q * 256 + tid);
      }
    if (tid < 33) segs[bid * 33 + tid] = c->clsofs[tid + 1];
  }
  __threadfence();
  grid.sync();

  // ---- S4: layer-1 class-sums + divisor LIF + compaction (block=batch) ----
  {
    SM_l1* L = (SM_l1*)smem;
    if (tid < 33) L->sseg[tid] = segs[bid * 33 + tid];
    __syncthreads();
    const int total = __builtin_amdgcn_readfirstlane(L->sseg[32]);
    for (int i = tid; i < total; i += 256)
      L->sidx[i] = lidx16[(size_t)bid * 1024 + i];
    __syncthreads();
    const int wave = tid >> 6, lane = tid & 63;
#pragma unroll 1
    for (int tile = 0; tile < 4; ++tile) {
      const int o = tile * 256 + tid;
      float S[32];
#pragma unroll
      for (int cc = 0; cc < 32; ++cc) {
        int j0 = __builtin_amdgcn_readfirstlane((cc == 0) ? 0 : L->sseg[cc - 1]);
        int j1 = __builtin_amdgcn_readfirstlane(L->sseg[cc]);
        float s = 0.f;
        for (int j = j0; j < j1; ++j)
          s += W1T[(size_t)L->sidx[j] * 1024 + o];
        S[cc] = s;
      }
      const float bias = b1[o];
      float v = 0.f;
      unsigned word = 0u;
#pragma unroll
      for (int t = 0; t < 32; ++t) {
        float cur = 0.f;
#pragma unroll
        for (int cc = 1; cc <= 32; ++cc)
          if ((t + 1) % cc == 0) cur += S[cc - 1];   // compile-time divisor table
        float xc = cur + bias;
        v = v + (xc - v) * 0.5f;
        if (v >= 1.0f) { word |= 1u << t; v = 0.f; }
      }
      bool act = (word != 0u);
      unsigned long long m = __ballot(act);
      if (lane == 0) L->wtot[wave] = __popcll(m);
      __syncthreads();
      if (tid == 0) {
        int s = 0;
#pragma unroll
        for (int i = 0; i < 4; ++i) { L->wbase[i] = s; s += L->wtot[i]; }
        n2t[bid * 4 + tile] = s;
      }
      __syncthreads();
      if (act) {
        int pos = L->wbase[wave] + __popcll(m & ((1ull << lane) - 1ull));
        l2idx[(size_t)bid * 1024 + tile * 256 + pos] = (unsigned)o;
        l2wrd[(size_t)bid * 1024 + tile * 256 + pos] = word;
      }
      __syncthreads();
    }
  }
  __threadfence();
  grid.sync();

  // ---- S5: layer-2 sparse FC + LIF + count (block=batch) ------------------
  {
    SM_l2* L = (SM_l2*)smem;
    int cnt[4], ofs[4], mtot = 0;
#pragma unroll
    for (int s = 0; s < 4; ++s) {
      cnt[s] = n2t[bid * 4 + s];
      ofs[s] = mtot;
      mtot += cnt[s];
    }
#pragma unroll
    for (int s = 0; s < 4; ++s)
      for (int i = tid; i < cnt[s]; i += 256) {
        L->sidx[ofs[s] + i] = l2idx[(size_t)bid * 1024 + s * 256 + i];
        L->swrd[ofs[s] + i] = l2wrd[(size_t)bid * 1024 + s * 256 + i];
      }
    __syncthreads();
    for (int i = tid; i < 320; i += 256) {
      int t = i / 10, c = i - t * 10;
      float acc = 0.f;
      for (int j = 0; j < mtot; ++j) {
        unsigned wd = L->swrd[j];
        float wv = W2[(size_t)c * 1024 + L->sidx[j]];   // 40 KB, L1/L2-hot
        acc += ((wd >> t) & 1u) ? wv : 0.f;
      }
      L->scur[i] = acc;
    }
    __syncthreads();
    if (tid < 10) {
      float v = 0.f, cnt2 = 0.f, bias = b2[tid];
#pragma unroll
      for (int tt = 0; tt < 32; ++tt) {
        float xc = L->scur[tt * 10 + tid] + bias;
        v = v + (xc - v) * 0.5f;
        if (v >= 1.0f) { cnt2 += 1.f; v = 0.f; }
      }
      out[(size_t)bid * 10 + tid] = cnt2;
    }
  }
}

// ======================= fallback 7-kernel path (R7, proven) ================
__global__ __launch_bounds__(256) void transpose_k(const float* __restrict__ src,
                                                   float* __restrict__ dst,
                                                   int R, int C) {
  __shared__ float t[32][33];
  int c0 = blockIdx.x * 32, r0 = blockIdx.y * 32;
  int lx = threadIdx.x, ly = threadIdx.y;
#pragma unroll
  for (int i = 0; i < 32; i += 8) {
    int r = r0 + ly + i, c = c0 + lx;
    if (r < R && c < C) t[ly + i][lx] = src[(size_t)r * C + c];
  }
  __syncthreads();
#pragma unroll
  for (int i = 0; i < 32; i += 8) {
    int c = c0 + ly + i, r = r0 + lx;
    if (c < C && r < R) dst[(size_t)c * R + r] = t[lx][ly + i];
  }
}

__global__ __launch_bounds__(256) void splitx_k(const float* __restrict__ x,
                                                __hip_bfloat16* __restrict__ Ax) {
  int i = blockIdx.x * 256 + threadIdx.x;
  int m = i / 800, k = i - m * 800;
  float v = (k < 784) ? x[(size_t)m * 784 + k] : 0.f;
  __hip_bfloat16 h, mm, l;
  bsplit3(v, h, mm, l);
  size_t base = (size_t)m * 4800;
  Ax[base + k] = h;         Ax[base + 800 + k] = h;
  Ax[base + 1600 + k] = mm; Ax[base + 2400 + k] = mm;
  Ax[base + 3200 + k] = h;  Ax[base + 4000 + k] = l;
}

__global__ __launch_bounds__(256) void splitw_k(const float* __restrict__ W0,
                                                __hip_bfloat16* __restrict__ Bw) {
  int i = blockIdx.x * 256 + threadIdx.x;
  int n = i / 800, k = i - n * 800;
  float v = (k < 784) ? W0[(size_t)n * 784 + k] : 0.f;
  __hip_bfloat16 h, mm, l;
  bsplit3(v, h, mm, l);
  size_t base = (size_t)n * 4800;
  Bw[base + k] = h;         Bw[base + 800 + k] = mm;
  Bw[base + 1600 + k] = h;  Bw[base + 2400 + k] = mm;
  Bw[base + 3200 + k] = l;  Bw[base + 4000 + k] = h;
}

__global__ __launch_bounds__(256, 2) void gemm0_k(const __hip_bfloat16* __restrict__ A,
                                                  const __hip_bfloat16* __restrict__ B,
                                                  float* __restrict__ Cpart) {
  __shared__ __align__(16) __hip_bfloat16 As[128 * 32];
  __shared__ __align__(16) __hip_bfloat16 Bs[128 * 32];
  const int tid = threadIdx.x;
  const int wave = tid >> 6, lane = tid & 63, quad = lane >> 4, l16 = lane & 15;
  const int wm = (wave >> 1) * 64, wn = (wave & 1) * 64;
  const int mbase = blockIdx.x * 128, nbase = blockIdx.y * 128;
  const int kbase = blockIdx.z * 480;
  const int srow = lane >> 2;
  const int gq = (lane & 3) ^ ((lane >> 3) & 3);
  const int swz = (l16 >> 1) & 3;
  f32x4 acc[4][4] = {};
  for (int kk = kbase; kk < kbase + 480; kk += 32) {
#pragma unroll
    for (int r = 0; r < 2; ++r) {
      int grp = wave * 2 + r;
      gload16(A + (size_t)(mbase + grp * 16 + srow) * 4800 + kk + gq * 8,
              (char*)As + grp * 1024);
      gload16(B + (size_t)(nbase + grp * 16 + srow) * 4800 + kk + gq * 8,
              (char*)Bs + grp * 1024);
    }
    __syncthreads();
    const __bf16* Ab = (const __bf16*)As;
    const __bf16* Bb = (const __bf16*)Bs;
    bf16x8 af[4], bfr[4];
#pragma unroll
    for (int i = 0; i < 4; ++i)
      af[i] = *(const bf16x8*)(Ab + (wm + i * 16 + l16) * 32 + ((quad ^ swz) * 8));
#pragma unroll
    for (int j = 0; j < 4; ++j)
      bfr[j] = *(const bf16x8*)(Bb + (wn + j * 16 + l16) * 32 + ((quad ^ swz) * 8));
#pragma unroll
    for (int i = 0; i < 4; ++i)
#pragma unroll
      for (int j = 0; j < 4; ++j)
        acc[i][j] = __builtin_amdgcn_mfma_f32_16x16x32_bf16(af[i], bfr[j], acc[i][j], 0, 0, 0);
    __syncthreads();
  }
  float* Cz = Cpart + (size_t)blockIdx.z * 512 * 1024;
#pragma unroll
  for (int i = 0; i < 4; ++i)
#pragma unroll
    for (int j = 0; j < 4; ++j)
#pragma unroll
      for (int r = 0; r < 4; ++r) {
        int m = mbase + wm + i * 16 + quad * 4 + r;
        int n = nbase + wn + j * 16 + l16;
        Cz[(size_t)m * 1024 + n] = acc[i][j][r];
      }
}

__global__ __launch_bounds__(1024) void compact0_k(const float* __restrict__ Cpart,
                                                   const float* __restrict__ b0,
                                                   unsigned short* __restrict__ lidx16,
                                                   int* __restrict__ segs) {
  __shared__ int whist[16][33];
  __shared__ int clstot[33];
  __shared__ int clsofs[34];
  __shared__ int wofs[16][33];
  int b = blockIdx.x, o = threadIdx.x;
  int wave = o >> 6, lane = o & 63;
  float cur = 0.f;
#pragma unroll
  for (int z = 0; z < 10; ++z)
    cur += Cpart[(size_t)z * 512 * 1024 + (size_t)b * 1024 + o];
  cur += b0[o];
  float v = 0.f;
  unsigned word = 0u;
#pragma unroll
  for (int t = 0; t < 32; ++t) {
    v = v + (cur - v) * 0.5f;
    if (v >= 1.0f) { word |= 1u << t; v = 0.f; }
  }
  int n = word ? (__builtin_ctz(word) + 1) : 0;
  unsigned long long mymask = 0ull;
#pragma unroll 1
  for (int c = 1; c <= 32; ++c) {
    unsigned long long m = __ballot(n == c);
    if (lane == 0) whist[wave][c] = __popcll(m);
    if (n == c) mymask = m;
  }
  __syncthreads();
  if (o < 32) {
    int c = o + 1, s = 0;
#pragma unroll
    for (int w = 0; w < 16; ++w) s += whist[w][c];
    clstot[c] = s;
  }
  __syncthreads();
  if (o == 0) {
    int run = 0;
#pragma unroll
    for (int c = 1; c <= 32; ++c) { clsofs[c] = run; run += clstot[c]; }
    clsofs[33] = run;
  }
  __syncthreads();
  if (o < 32) {
    int c = o + 1, s = clsofs[c];
#pragma unroll
    for (int w = 0; w < 16; ++w) { wofs[w][c] = s; s += whist[w][c]; }
  }
  __syncthreads();
  if (n) {
    int pos = wofs[wave][n] + __popcll(mymask & ((1ull << lane) - 1ull));
    lidx16[(size_t)b * 1024 + pos] = (unsigned short)o;
  }
  if (o < 33) segs[b * 33 + o] = clsofs[o + 1];
}

__global__ __launch_bounds__(256) void layer1_k(const unsigned short* __restrict__ lidx16,
                                                const int* __restrict__ segs,
                                                const float* __restrict__ W1T,
                                                const float* __restrict__ b1,
                                                unsigned* __restrict__ l2idx,
                                                unsigned* __restrict__ l2wrd,
                                                int* __restrict__ n2t) {
  __shared__ unsigned short sidx[1024];
  __shared__ int sseg[33];
  __shared__ int wtot[4], wbase[4];
  const int tile = blockIdx.x, b = blockIdx.y;
  const int tid = threadIdx.x;
  const int o = tile * 256 + tid;
  if (tid < 33) sseg[tid] = segs[b * 33 + tid];
  __syncthreads();
  const int total = __builtin_amdgcn_readfirstlane(sseg[32]);
  for (int i = tid; i < total; i += 256)
    sidx[i] = lidx16[(size_t)b * 1024 + i];
  __syncthreads();
  float S[32];
#pragma unroll
  for (int c = 0; c < 32; ++c) {
    int j0 = __builtin_amdgcn_readfirstlane((c == 0) ? 0 : sseg[c - 1]);
    int j1 = __builtin_amdgcn_readfirstlane(sseg[c]);
    float s = 0.f;
    for (int j = j0; j < j1; ++j)
      s += W1T[(size_t)sidx[j] * 1024 + o];
    S[c] = s;
  }
  const float bias = b1[o];
  float v = 0.f;
  unsigned word = 0u;
#pragma unroll
  for (int t = 0; t < 32; ++t) {
    float cur = 0.f;
#pragma unroll
    for (int c = 1; c <= 32; ++c)
      if ((t + 1) % c == 0) cur += S[c - 1];
    float xc = cur + bias;
    v = v + (xc - v) * 0.5f;
    if (v >= 1.0f) { word |= 1u << t; v = 0.f; }
  }
  bool act = (word != 0u);
  unsigned long long m = __ballot(act);
  int wave = tid >> 6, lane = tid & 63;
  if (lane == 0) wtot[wave] = __popcll(m);
  __syncthreads();
  if (tid == 0) {
    int s = 0;
#pragma unroll
    for (int i = 0; i < 4; ++i) { wbase[i] = s; s += wtot[i]; }
    n2t[b * 4 + tile] = s;
  }
  __syncthreads();
  if (act) {
    int pos = wbase[wave] + __popcll(m & ((1ull << lane) - 1ull));
    l2idx[(size_t)b * 1024 + tile * 256 + pos] = (unsigned)o;
    l2wrd[(size_t)b * 1024 + tile * 256 + pos] = word;
  }
}

__global__ __launch_bounds__(320) void layer2_k(const unsigned* __restrict__ l2idx,
                                                const unsigned* __restrict__ l2wrd,
                                                const int* __restrict__ n2t,
                                                const float* __restrict__ W2,
                                                const float* __restrict__ b2,
                                                float* __restrict__ out) {
  __shared__ float sW2[10 * 1025];
  __shared__ unsigned sidx[1024], swrd[1024];
  __shared__ float scur[320];
  int b = blockIdx.x, tid = threadIdx.x;
  int cnt[4], ofs[4], mtot = 0;
#pragma unroll
  for (int s = 0; s < 4; ++s) {
    cnt[s] = n2t[b * 4 + s];
    ofs[s] = mtot;
    mtot += cnt[s];
  }
  for (int i = tid; i < 10240; i += 320)
    sW2[(i >> 10) * 1025 + (i & 1023)] = W2[i];
#pragma unroll
  for (int s = 0; s < 4; ++s)
    for (int i = tid; i < cnt[s]; i += 320) {
      sidx[ofs[s] + i] = l2idx[(size_t)b * 1024 + s * 256 + i];
      swrd[ofs[s] + i] = l2wrd[(size_t)b * 1024 + s * 256 + i];
    }
  __syncthreads();
  int t = tid / 10, c = tid - t * 10;
  float acc = 0.f;
  for (int j = 0; j < mtot; ++j) {
    unsigned wd = swrd[j];
    float wv = sW2[c * 1025 + sidx[j]];
    acc += ((wd >> t) & 1u) ? wv : 0.f;
  }
  scur[t * 10 + c] = acc;
  __syncthreads();
  if (tid < 10) {
    float v = 0.f, cnt2 = 0.f, bias = b2[tid];
#pragma unroll
    for (int tt = 0; tt < 32; ++tt) {
      float xc = scur[tt * 10 + tid] + bias;
      v = v + (xc - v) * 0.5f;
      if (v >= 1.0f) { cnt2 += 1.f; v = 0.f; }
    }
    out[(size_t)b * 10 + tid] = cnt2;
  }
}

// ---------------------------------------------------------------------------
extern "C" void kernel_launch(void* const* d_in, const int* in_sizes, int n_in,
                              void* d_out, int out_size, void* d_ws, size_t ws_size,
                              hipStream_t stream) {
  const float* x  = (const float*)d_in[0];
  const float* W0 = (const float*)d_in[1];
  const float* b0 = (const float*)d_in[2];
  const float* W1 = (const float*)d_in[3];
  const float* b1 = (const float*)d_in[4];
  const float* W2 = (const float*)d_in[5];
  const float* b2 = (const float*)d_in[6];
  float* out = (float*)d_out;

  char* ws = (char*)d_ws;
  size_t off = 0;
  auto alloc = [&](size_t bytes) -> char* {
    char* p = ws + off;
    off += (bytes + 255) & ~(size_t)255;
    return p;
  };
  __hip_bfloat16* Ax     = (__hip_bfloat16*)alloc((size_t)512 * 4800 * 2);
  __hip_bfloat16* Bw     = (__hip_bfloat16*)alloc((size_t)1024 * 4800 * 2);
  float*          Cpart  = (float*)alloc((size_t)10 * 512 * 1024 * 4);
  float*          W1T    = (float*)alloc((size_t)1024 * 1024 * 4);
  unsigned short* lidx16 = (unsigned short*)alloc((size_t)512 * 1024 * 2);
  int*            segs   = (int*)alloc((size_t)512 * 33 * 4);
  unsigned*       l2idx  = (unsigned*)alloc((size_t)512 * 1024 * 4);
  unsigned*       l2wrd  = (unsigned*)alloc((size_t)512 * 1024 * 4);
  int*            n2t    = (int*)alloc((size_t)512 * 4 * 4);
  (void)ws_size;

  void* args[] = {&x, &W0, &b0, &W1, &b1, &W2, &b2, &out,
                  &Ax, &Bw, &Cpart, &W1T, &lidx16, &segs, &l2idx, &l2wrd, &n2t};
  hipError_t e = hipLaunchCooperativeKernel((void*)snn_mega_k, dim3(512), dim3(256),
                                            args, 0, stream);
  if (e != hipSuccess) {
    // fallback: proven R7 multi-kernel path (same buffers, same results)
    splitx_k<<<1600, 256, 0, stream>>>(x, Ax);
    splitw_k<<<3200, 256, 0, stream>>>(W0, Bw);
    transpose_k<<<dim3(32, 32), dim3(32, 8), 0, stream>>>(W1, W1T, 1024, 1024);
    gemm0_k<<<dim3(4, 8, 10), 256, 0, stream>>>(Ax, Bw, Cpart);
    compact0_k<<<512, 1024, 0, stream>>>(Cpart, b0, lidx16, segs);
    layer1_k<<<dim3(4, 512), 256, 0, stream>>>(lidx16, segs, W1T, b1, l2idx, l2wrd, n2t);
    layer2_k<<<512, 320, 0, stream>>>(l2idx, l2wrd, n2t, W2, b2, out);
  }
}

// Round 9
// 117.671 us; speedup vs baseline: 4.9418x; 4.9418x over previous
//
#include <hip/hip_runtime.h>
#include <hip/hip_bf16.h>
#include <stdint.h>

// ---------------------------------------------------------------------------
// SNN: x[512,784] -> FC(784->1024)+LIF -> FC(1024->1024)+LIF -> FC(1024->10)+LIF
// T=32, tau=2, vth=1, hard reset. Out = spike counts [512,10].
//
// Verified structure (R5-R7, absmax=0): layer-0 LIF exactly periodic (class
// n = ctz(word)+1); layer-1 current = divisor sum over class weight-sums;
// cur0 via exact 3-way bf16 split (6 cross-terms) MFMA GEMM, split-K x10.
//
// R8 lesson: cooperative grid.sync() costs ~100us each on this target
// (503us mega-kernel, VALUBusy 3%) -> NEVER trade launches for grid-wide
// barriers here. Inter-kernel gap ~4us is the cheap primitive.
// R9: R7 structure, but the 3 independent prep kernels (splitx/splitw/W1T)
// fused into ONE grid-partitioned kernel: 7 kernels/6 gaps -> 5 kernels/4.
// ---------------------------------------------------------------------------

typedef __bf16 bf16x8 __attribute__((ext_vector_type(8)));
typedef float  f32x4  __attribute__((ext_vector_type(4)));

__device__ __forceinline__ void gload16(const void* g, void* l) {
  __builtin_amdgcn_global_load_lds((const __attribute__((address_space(1))) void*)g,
                                   (__attribute__((address_space(3))) void*)l,
                                   16, 0, 0);
}

__device__ __forceinline__ void bsplit3(float v, __hip_bfloat16& h,
                                        __hip_bfloat16& m, __hip_bfloat16& l) {
  h = __float2bfloat16(v);
  float r1 = v - __bfloat162float(h);
  m = __float2bfloat16(r1);
  float r2 = r1 - __bfloat162float(m);
  l = __float2bfloat16(r2);
}

// ---------------- prep: bf16 splits of x & W0 + W1 transpose (one kernel) ---
// Block-uniform partition: [0,1600) splitx, [1600,4800) splitw,
// [4800,5824) W1-transpose 32x32 tiles. All outputs independent.
__global__ __launch_bounds__(256) void prep_k(const float* __restrict__ x,
                                              const float* __restrict__ W0,
                                              const float* __restrict__ W1,
                                              __hip_bfloat16* __restrict__ Ax,
                                              __hip_bfloat16* __restrict__ Bw,
                                              float* __restrict__ W1T) {
  const int bid = blockIdx.x, tid = threadIdx.x;
  if (bid < 1600) {                       // splitx: 512*800 elements
    int i = bid * 256 + tid;
    int m = i / 800, k = i - m * 800;
    float v = (k < 784) ? x[(size_t)m * 784 + k] : 0.f;
    __hip_bfloat16 h, mm, l;
    bsplit3(v, h, mm, l);
    size_t base = (size_t)m * 4800;
    Ax[base + k] = h;         Ax[base + 800 + k] = h;
    Ax[base + 1600 + k] = mm; Ax[base + 2400 + k] = mm;
    Ax[base + 3200 + k] = h;  Ax[base + 4000 + k] = l;
  } else if (bid < 4800) {                // splitw: 1024*800 elements
    int i = (bid - 1600) * 256 + tid;
    int n = i / 800, k = i - n * 800;
    float v = (k < 784) ? W0[(size_t)n * 784 + k] : 0.f;
    __hip_bfloat16 h, mm, l;
    bsplit3(v, h, mm, l);
    size_t base = (size_t)n * 4800;
    Bw[base + k] = h;         Bw[base + 800 + k] = mm;
    Bw[base + 1600 + k] = h;  Bw[base + 2400 + k] = mm;
    Bw[base + 3200 + k] = l;  Bw[base + 4000 + k] = h;
  } else {                                // W1 transpose: 1024 32x32 tiles
    __shared__ float t[32][33];
    int tt = bid - 4800;
    int c0 = (tt & 31) * 32, r0 = (tt >> 5) * 32;
    int lx = tid & 31, ly = tid >> 5;     // 32 x 8
#pragma unroll
    for (int i = 0; i < 32; i += 8)
      t[ly + i][lx] = W1[(size_t)(r0 + ly + i) * 1024 + (c0 + lx)];
    __syncthreads();
#pragma unroll
    for (int i = 0; i < 32; i += 8)
      W1T[(size_t)(c0 + ly + i) * 1024 + (r0 + lx)] = t[lx][ly + i];
  }
}

// ---------------- gemm0 split-K: partial[z] = Ax x Bw^T over K-chunk z ------
// 128x128 tile, BK=32, global_load_lds(16B), XOR quad swizzle. Grid (4,8,10)
// = 320 blocks (~1.25/CU).
__global__ __launch_bounds__(256, 2) void gemm0_k(const __hip_bfloat16* __restrict__ A,
                                                  const __hip_bfloat16* __restrict__ B,
                                                  float* __restrict__ Cpart) {
  __shared__ __align__(16) __hip_bfloat16 As[128 * 32];
  __shared__ __align__(16) __hip_bfloat16 Bs[128 * 32];
  const int tid = threadIdx.x;
  const int wave = tid >> 6, lane = tid & 63, quad = lane >> 4, l16 = lane & 15;
  const int wm = (wave >> 1) * 64, wn = (wave & 1) * 64;
  const int mbase = blockIdx.x * 128, nbase = blockIdx.y * 128;
  const int kbase = blockIdx.z * 480;
  const int srow = lane >> 2;
  const int gq = (lane & 3) ^ ((lane >> 3) & 3);
  const int swz = (l16 >> 1) & 3;
  f32x4 acc[4][4] = {};
  for (int kk = kbase; kk < kbase + 480; kk += 32) {
#pragma unroll
    for (int r = 0; r < 2; ++r) {
      int grp = wave * 2 + r;
      gload16(A + (size_t)(mbase + grp * 16 + srow) * 4800 + kk + gq * 8,
              (char*)As + grp * 1024);
      gload16(B + (size_t)(nbase + grp * 16 + srow) * 4800 + kk + gq * 8,
              (char*)Bs + grp * 1024);
    }
    __syncthreads();
    const __bf16* Ab = (const __bf16*)As;
    const __bf16* Bb = (const __bf16*)Bs;
    bf16x8 af[4], bfr[4];
#pragma unroll
    for (int i = 0; i < 4; ++i)
      af[i] = *(const bf16x8*)(Ab + (wm + i * 16 + l16) * 32 + ((quad ^ swz) * 8));
#pragma unroll
    for (int j = 0; j < 4; ++j)
      bfr[j] = *(const bf16x8*)(Bb + (wn + j * 16 + l16) * 32 + ((quad ^ swz) * 8));
#pragma unroll
    for (int i = 0; i < 4; ++i)
#pragma unroll
      for (int j = 0; j < 4; ++j)
        acc[i][j] = __builtin_amdgcn_mfma_f32_16x16x32_bf16(af[i], bfr[j], acc[i][j], 0, 0, 0);
    __syncthreads();
  }
  float* Cz = Cpart + (size_t)blockIdx.z * 512 * 1024;
#pragma unroll
  for (int i = 0; i < 4; ++i)
#pragma unroll
    for (int j = 0; j < 4; ++j)
#pragma unroll
      for (int r = 0; r < 4; ++r) {
        int m = mbase + wm + i * 16 + quad * 4 + r;
        int n = nbase + wn + j * 16 + l16;
        Cz[(size_t)m * 1024 + n] = acc[i][j][r];
      }
}

// ---------------- layer-0: split-K reduce + LIF + class compaction ----------
__global__ __launch_bounds__(1024) void compact0_k(const float* __restrict__ Cpart,
                                                   const float* __restrict__ b0,
                                                   unsigned short* __restrict__ lidx16,
                                                   int* __restrict__ segs) {
  __shared__ int whist[16][33];
  __shared__ int clstot[33];
  __shared__ int clsofs[34];
  __shared__ int wofs[16][33];
  int b = blockIdx.x, o = threadIdx.x;
  int wave = o >> 6, lane = o & 63;
  float cur = 0.f;
#pragma unroll
  for (int z = 0; z < 10; ++z)
    cur += Cpart[(size_t)z * 512 * 1024 + (size_t)b * 1024 + o];
  cur += b0[o];
  float v = 0.f;
  unsigned word = 0u;
#pragma unroll
  for (int t = 0; t < 32; ++t) {
    v = v + (cur - v) * 0.5f;            // exact: /2.0 == *0.5f
    if (v >= 1.0f) { word |= 1u << t; v = 0.f; }
  }
  int n = word ? (__builtin_ctz(word) + 1) : 0;
  unsigned long long mymask = 0ull;
#pragma unroll 1
  for (int c = 1; c <= 32; ++c) {
    unsigned long long m = __ballot(n == c);
    if (lane == 0) whist[wave][c] = __popcll(m);
    if (n == c) mymask = m;
  }
  __syncthreads();
  if (o < 32) {
    int c = o + 1, s = 0;
#pragma unroll
    for (int w = 0; w < 16; ++w) s += whist[w][c];
    clstot[c] = s;
  }
  __syncthreads();
  if (o == 0) {
    int run = 0;
#pragma unroll
    for (int c = 1; c <= 32; ++c) { clsofs[c] = run; run += clstot[c]; }
    clsofs[33] = run;
  }
  __syncthreads();
  if (o < 32) {
    int c = o + 1, s = clsofs[c];
#pragma unroll
    for (int w = 0; w < 16; ++w) { wofs[w][c] = s; s += whist[w][c]; }
  }
  __syncthreads();
  if (n) {
    int pos = wofs[wave][n] + __popcll(mymask & ((1ull << lane) - 1ull));
    lidx16[(size_t)b * 1024 + pos] = (unsigned short)o;
  }
  if (o < 33) segs[b * 33 + o] = clsofs[o + 1];
}

// ---------------- layer-1: class-sum + divisor-table LIF + compaction -------
__global__ __launch_bounds__(256) void layer1_k(const unsigned short* __restrict__ lidx16,
                                                const int* __restrict__ segs,
                                                const float* __restrict__ W1T,
                                                const float* __restrict__ b1,
                                                unsigned* __restrict__ l2idx,
                                                unsigned* __restrict__ l2wrd,
                                                int* __restrict__ n2t) {
  __shared__ unsigned short sidx[1024];
  __shared__ int sseg[33];
  __shared__ int wtot[4], wbase[4];
  const int tile = blockIdx.x, b = blockIdx.y;
  const int tid = threadIdx.x;
  const int o = tile * 256 + tid;
  if (tid < 33) sseg[tid] = segs[b * 33 + tid];
  __syncthreads();
  const int total = __builtin_amdgcn_readfirstlane(sseg[32]);
  for (int i = tid; i < total; i += 256)
    sidx[i] = lidx16[(size_t)b * 1024 + i];
  __syncthreads();
  float S[32];
#pragma unroll
  for (int c = 0; c < 32; ++c) {
    int j0 = __builtin_amdgcn_readfirstlane((c == 0) ? 0 : sseg[c - 1]);
    int j1 = __builtin_amdgcn_readfirstlane(sseg[c]);
    float s = 0.f;
    for (int j = j0; j < j1; ++j)
      s += W1T[(size_t)sidx[j] * 1024 + o];
    S[c] = s;
  }
  const float bias = b1[o];
  float v = 0.f;
  unsigned word = 0u;
#pragma unroll
  for (int t = 0; t < 32; ++t) {
    float cur = 0.f;
#pragma unroll
    for (int c = 1; c <= 32; ++c)
      if ((t + 1) % c == 0) cur += S[c - 1];   // compile-time divisor table
    float xc = cur + bias;
    v = v + (xc - v) * 0.5f;
    if (v >= 1.0f) { word |= 1u << t; v = 0.f; }
  }
  bool act = (word != 0u);
  unsigned long long m = __ballot(act);
  int wave = tid >> 6, lane = tid & 63;
  if (lane == 0) wtot[wave] = __popcll(m);
  __syncthreads();
  if (tid == 0) {
    int s = 0;
#pragma unroll
    for (int i = 0; i < 4; ++i) { wbase[i] = s; s += wtot[i]; }
    n2t[b * 4 + tile] = s;
  }
  __syncthreads();
  if (act) {
    int pos = wbase[wave] + __popcll(m & ((1ull << lane) - 1ull));
    l2idx[(size_t)b * 1024 + tile * 256 + pos] = (unsigned)o;
    l2wrd[(size_t)b * 1024 + tile * 256 + pos] = word;
  }
}

// ---------------- layer-2: sparse FC + LIF + count --------------------------
__global__ __launch_bounds__(320) void layer2_k(const unsigned* __restrict__ l2idx,
                                                const unsigned* __restrict__ l2wrd,
                                                const int* __restrict__ n2t,
                                                const float* __restrict__ W2,
                                                const float* __restrict__ b2,
                                                float* __restrict__ out) {
  __shared__ float sW2[10 * 1025];
  __shared__ unsigned sidx[1024], swrd[1024];
  __shared__ float scur[320];
  int b = blockIdx.x, tid = threadIdx.x;
  int cnt[4], ofs[4], mtot = 0;
#pragma unroll
  for (int s = 0; s < 4; ++s) {
    cnt[s] = n2t[b * 4 + s];
    ofs[s] = mtot;
    mtot += cnt[s];
  }
  for (int i = tid; i < 10240; i += 320)
    sW2[(i >> 10) * 1025 + (i & 1023)] = W2[i];
#pragma unroll
  for (int s = 0; s < 4; ++s)
    for (int i = tid; i < cnt[s]; i += 320) {
      sidx[ofs[s] + i] = l2idx[(size_t)b * 1024 + s * 256 + i];
      swrd[ofs[s] + i] = l2wrd[(size_t)b * 1024 + s * 256 + i];
    }
  __syncthreads();
  int t = tid / 10, c = tid - t * 10;
  float acc = 0.f;
  for (int j = 0; j < mtot; ++j) {
    unsigned wd = swrd[j];
    float wv = sW2[c * 1025 + sidx[j]];
    acc += ((wd >> t) & 1u) ? wv : 0.f;
  }
  scur[t * 10 + c] = acc;
  __syncthreads();
  if (tid < 10) {
    float v = 0.f, cnt2 = 0.f, bias = b2[tid];
#pragma unroll
    for (int tt = 0; tt < 32; ++tt) {
      float xc = scur[tt * 10 + tid] + bias;
      v = v + (xc - v) * 0.5f;
      if (v >= 1.0f) { cnt2 += 1.f; v = 0.f; }
    }
    out[(size_t)b * 10 + tid] = cnt2;
  }
}

// ---------------------------------------------------------------------------
extern "C" void kernel_launch(void* const* d_in, const int* in_sizes, int n_in,
                              void* d_out, int out_size, void* d_ws, size_t ws_size,
                              hipStream_t stream) {
  const float* x  = (const float*)d_in[0];
  const float* W0 = (const float*)d_in[1];
  const float* b0 = (const float*)d_in[2];
  const float* W1 = (const float*)d_in[3];
  const float* b1 = (const float*)d_in[4];
  const float* W2 = (const float*)d_in[5];
  const float* b2 = (const float*)d_in[6];
  float* out = (float*)d_out;

  char* ws = (char*)d_ws;
  size_t off = 0;
  auto alloc = [&](size_t bytes) -> char* {
    char* p = ws + off;
    off += (bytes + 255) & ~(size_t)255;
    return p;
  };
  __hip_bfloat16* Ax     = (__hip_bfloat16*)alloc((size_t)512 * 4800 * 2);
  __hip_bfloat16* Bw     = (__hip_bfloat16*)alloc((size_t)1024 * 4800 * 2);
  float*          Cpart  = (float*)alloc((size_t)10 * 512 * 1024 * 4);
  float*          W1T    = (float*)alloc((size_t)1024 * 1024 * 4);
  unsigned short* lidx16 = (unsigned short*)alloc((size_t)512 * 1024 * 2);
  int*            segs   = (int*)alloc((size_t)512 * 33 * 4);
  unsigned*       l2idx  = (unsigned*)alloc((size_t)512 * 1024 * 4);
  unsigned*       l2wrd  = (unsigned*)alloc((size_t)512 * 1024 * 4);
  int*            n2t    = (int*)alloc((size_t)512 * 4 * 4);
  (void)ws_size;

  prep_k<<<5824, 256, 0, stream>>>(x, W0, W1, Ax, Bw, W1T);
  gemm0_k<<<dim3(4, 8, 10), 256, 0, stream>>>(Ax, Bw, Cpart);
  compact0_k<<<512, 1024, 0, stream>>>(Cpart, b0, lidx16, segs);
  layer1_k<<<dim3(4, 512), 256, 0, stream>>>(lidx16, segs, W1T, b1, l2idx, l2wrd, n2t);
  layer2_k<<<512, 320, 0, stream>>>(l2idx, l2wrd, n2t, W2, b2, out);
}